// Round 10
// baseline (627.494 us; speedup 1.0000x reference)
//
#include <hip/hip_runtime.h>

#define K_TPLT 16
#define M_NODES 10
#define DFEAT 128
#define NMAXW 4           // node-blocks per wave (2 waves x 4 x 64 = 512 >= 448)
#define N_ITER 50
#define NEG_BIG -1e30f
#define LOG2E 1.44269504088896340736f
#define LN2   0.69314718055994530942f

#define EXP2F(x) __builtin_amdgcn_exp2f(x)
#define LOG2F(x) __builtin_amdgcn_logf(x)   // v_log_f32 = log base 2

__global__ void zero_counts_k(int* counts, int G) {
    int g = blockIdx.x * blockDim.x + threadIdx.x;
    if (g < G) counts[g] = 0;
}

__global__ void count_nodes_k(const int* __restrict__ batch, int* counts, int N) {
    int i = blockIdx.x * blockDim.x + threadIdx.x;
    if (i < N) atomicAdd(&counts[batch[i]], 1);
}

__global__ void scan_counts_k(const int* __restrict__ counts, int* starts, int G) {
    __shared__ int sc[1024];
    int t = threadIdx.x;
    for (int g = t; g < G; g += blockDim.x) sc[g] = counts[g];
    __syncthreads();
    for (int g = t; g < G; g += blockDim.x) {
        int s = 0;
        for (int j = 0; j < g; ++j) s += sc[j];
        starts[g] = s;
    }
}

// 2 waves per (graph, template) problem; wave w owns node-blocks 4w..4w+3.
// Per-column partial sums are combined via a parity-double-buffered LDS slot
// with ONE barrier per iteration (all problems run a fixed 50 iterations, so
// barriers are block-uniform; WAR hazards separated by the alternating slot).
// Iteration math identical to the verified R7 kernel: log-domain L (row max
// 0), fresh per-node row shift each iteration, exact update with +g2[m],
// iteration-1 exact via problem-global csh (LDS max-combined).
__global__ __launch_bounds__(128) void sinkhorn_tw_k(
    const float* __restrict__ x, const float* __restrict__ tplt,
    const float* __restrict__ q0, const int* __restrict__ starts,
    const int* __restrict__ counts, float* __restrict__ out, int G)
{
    const int bid  = blockIdx.x;
    const int g    = bid % G;      // same-g blocks land on same XCD (G % 8 == 0)
    const int k    = bid / G;
    const int w    = threadIdx.x >> 6;        // wave id within problem: 0/1
    const int lane = threadIdx.x & 63;

    __shared__ float sm[2][2][M_NODES];       // [parity][wave][m]

    const int start = starts[g];
    const int count = counts[g];
    const float a   = 1.0f / (float)count;
    const float la2 = -LOG2F((float)count);            // log2(a)

    // lbla[m] = log2_softmax(q0[k,:]) - la2   (duplicated in both waves)
    const float* qk = q0 + k * M_NODES;
    float lbla[M_NODES];
    {
        float qv[M_NODES];
        float qmax = NEG_BIG;
#pragma unroll
        for (int m = 0; m < M_NODES; ++m) { qv[m] = qk[m]; qmax = fmaxf(qmax, qv[m]); }
        float qs = 0.f;
#pragma unroll
        for (int m = 0; m < M_NODES; ++m) {
            qv[m] = (qv[m] - qmax) * LOG2E;
            qs += EXP2F(qv[m]);
        }
        const float corr = LOG2F(qs);
#pragma unroll
        for (int m = 0; m < M_NODES; ++m) lbla[m] = qv[m] - corr - la2;
    }

    bool act[NMAXW];
#pragma unroll
    for (int j = 0; j < NMAXW; ++j) act[j] = (lane + 64 * (4 * w + j)) < count;

    // L[j][m] = (negC * log2e) - nsh_j  (log2 domain, <= 0, row max == 0)
    float L[NMAXW][M_NODES];
    float nsh[NMAXW];
    float csh[M_NODES];
    {
        const float* Tk = tplt + (size_t)k * M_NODES * DFEAT;
        float x2[NMAXW];
        float t2[M_NODES];
#pragma unroll
        for (int j = 0; j < NMAXW; ++j) {
            x2[j] = 0.f;
#pragma unroll
            for (int m = 0; m < M_NODES; ++m) L[j][m] = 0.f;
        }
#pragma unroll
        for (int m = 0; m < M_NODES; ++m) t2[m] = 0.f;

        for (int jf = 0; jf < DFEAT; jf += 4) {
            float4 xv[NMAXW];
#pragma unroll
            for (int j = 0; j < NMAXW; ++j) {
                if (act[j]) {
                    xv[j] = *(const float4*)(x + (size_t)(start + lane + 64 * (4 * w + j)) * DFEAT + jf);
                } else {
                    xv[j].x = xv[j].y = xv[j].z = xv[j].w = 0.f;
                }
                x2[j] += xv[j].x * xv[j].x + xv[j].y * xv[j].y
                       + xv[j].z * xv[j].z + xv[j].w * xv[j].w;
            }
#pragma unroll
            for (int m = 0; m < M_NODES; ++m) {
                const float4 tv = *(const float4*)(Tk + m * DFEAT + jf);
                t2[m] += tv.x * tv.x + tv.y * tv.y + tv.z * tv.z + tv.w * tv.w;
#pragma unroll
                for (int j = 0; j < NMAXW; ++j) {
                    L[j][m] += xv[j].x * tv.x + xv[j].y * tv.y
                             + xv[j].z * tv.z + xv[j].w * tv.w;
                }
            }
        }
#pragma unroll
        for (int j = 0; j < NMAXW; ++j) {
            float mx = NEG_BIG;
#pragma unroll
            for (int m = 0; m < M_NODES; ++m) {
                L[j][m] = (2.f * L[j][m] - x2[j] - t2[m]) * LOG2E;   // negC2
                mx = fmaxf(mx, L[j][m]);
            }
            nsh[j] = mx;
#pragma unroll
            for (int m = 0; m < M_NODES; ++m) L[j][m] -= mx;         // <= 0
        }
        // csh_m = problem-global column max of L: wave-local -> LDS combine
#pragma unroll
        for (int m = 0; m < M_NODES; ++m) {
            float c = NEG_BIG;
#pragma unroll
            for (int j = 0; j < NMAXW; ++j) c = act[j] ? fmaxf(c, L[j][m]) : c;
            for (int off = 32; off > 0; off >>= 1) c = fmaxf(c, __shfl_xor(c, off));
            csh[m] = c;
        }
        if (lane == 0) {
#pragma unroll
            for (int m = 0; m < M_NODES; ++m) sm[1][w][m] = csh[m];
        }
        __syncthreads();
#pragma unroll
        for (int m = 0; m < M_NODES; ++m) csh[m] = fmaxf(sm[1][0][m], sm[1][1][m]);
    }

    float g2[M_NODES];

    // ---- iteration 0: g = 0, exact with per-column shift csh (slot 0) ----
    {
        float w0[M_NODES], acc[M_NODES];
#pragma unroll
        for (int m = 0; m < M_NODES; ++m) { w0[m] = EXP2F(csh[m]); acc[m] = 0.f; }
#pragma unroll
        for (int j = 0; j < NMAXW; ++j) {
            if (act[j]) {
                float E[M_NODES];
                float D = 0.f;
#pragma unroll
                for (int m = 0; m < M_NODES; ++m) {
                    E[m] = EXP2F(L[j][m] - csh[m]);     // <= 1, col max == 1
                    D = fmaf(E[m], w0[m], D);           // = sum 2^L, >= 1
                }
                const float r = __builtin_amdgcn_rcpf(D);
#pragma unroll
                for (int m = 0; m < M_NODES; ++m) acc[m] = fmaf(E[m], r, acc[m]);
            }
        }
#pragma unroll
        for (int m = 0; m < M_NODES; ++m) {
            for (int off = 32; off > 0; off >>= 1) acc[m] += __shfl_xor(acc[m], off);
        }
        if (lane == 0) {
#pragma unroll
            for (int m = 0; m < M_NODES; ++m) sm[0][w][m] = acc[m];
        }
        __syncthreads();
#pragma unroll
        for (int m = 0; m < M_NODES; ++m) {
            const float s = sm[0][0][m] + sm[0][1][m];
            g2[m] = lbla[m] - csh[m] - LOG2F(fmaxf(s, 1e-35f));
        }
    }

    // ---- iterations 1..49: fresh per-node row shift; slot = it&1 ----
    for (int it = 1; it < N_ITER; ++it) {
        float acc[M_NODES];
#pragma unroll
        for (int m = 0; m < M_NODES; ++m) acc[m] = 0.f;

#pragma unroll
        for (int j = 0; j < NMAXW; ++j) {
            if (act[j]) {
                float e[M_NODES];
                float zmax = NEG_BIG;
#pragma unroll
                for (int m = 0; m < M_NODES; ++m) {
                    e[m] = g2[m] + L[j][m];
                    zmax = fmaxf(zmax, e[m]);
                }
                float D = 0.f;
#pragma unroll
                for (int m = 0; m < M_NODES; ++m) { e[m] = EXP2F(e[m] - zmax); D += e[m]; }
                const float r = __builtin_amdgcn_rcpf(D);   // D in [1,10]
#pragma unroll
                for (int m = 0; m < M_NODES; ++m) acc[m] = fmaf(e[m], r, acc[m]);
            }
        }
#pragma unroll
        for (int m = 0; m < M_NODES; ++m) {
            for (int off = 32; off > 0; off >>= 1) acc[m] += __shfl_xor(acc[m], off);
        }
        const int p = it & 1;
        if (lane == 0) {
#pragma unroll
            for (int m = 0; m < M_NODES; ++m) sm[p][w][m] = acc[m];
        }
        __syncthreads();
#pragma unroll
        for (int m = 0; m < M_NODES; ++m) {
            const float s = sm[p][0][m] + sm[p][1][m];
            g2[m] = lbla[m] + g2[m] - LOG2F(fmaxf(s, 1e-35f));  // exact update
        }
    }

    // ---- epilogue: final f fused with transport cost (slot 0) ----
    // per_node = -a*ln2*( nsh_j + r * sum_m e_m L_m )
    float accum = 0.f;
#pragma unroll
    for (int j = 0; j < NMAXW; ++j) {
        if (act[j]) {
            float e[M_NODES];
            float zmax = NEG_BIG;
#pragma unroll
            for (int m = 0; m < M_NODES; ++m) {
                e[m] = g2[m] + L[j][m];
                zmax = fmaxf(zmax, e[m]);
            }
            float D = 0.f;
#pragma unroll
            for (int m = 0; m < M_NODES; ++m) { e[m] = EXP2F(e[m] - zmax); D += e[m]; }
            const float r = __builtin_amdgcn_rcpf(D);
            float q = 0.f;
#pragma unroll
            for (int m = 0; m < M_NODES; ++m) q = fmaf(e[m], L[j][m], q);
            accum += nsh[j] + q * r;
        }
    }
    for (int off = 32; off > 0; off >>= 1) accum += __shfl_xor(accum, off);
    if (lane == 0) sm[0][w][0] = accum;
    __syncthreads();
    if (w == 0 && lane == 0)
        out[(size_t)g * K_TPLT + k] = -a * LN2 * (sm[0][0][0] + sm[0][1][0]);
}

extern "C" void kernel_launch(void* const* d_in, const int* in_sizes, int n_in,
                              void* d_out, int out_size, void* d_ws, size_t ws_size,
                              hipStream_t stream) {
    const float* x    = (const float*)d_in[0];
    const float* tplt = (const float*)d_in[1];
    const float* q0   = (const float*)d_in[2];
    const int* batch  = (const int*)d_in[3];
    const int N = in_sizes[3];
    const int G = out_size / K_TPLT;

    int* counts = (int*)d_ws;
    int* starts = counts + G;

    zero_counts_k<<<(G + 255) / 256, 256, 0, stream>>>(counts, G);
    count_nodes_k<<<(N + 255) / 256, 256, 0, stream>>>(batch, counts, N);
    scan_counts_k<<<1, 256, 0, stream>>>(counts, starts, G);
    sinkhorn_tw_k<<<G * K_TPLT, 128, 0, stream>>>(x, tplt, q0, starts, counts,
                                                  (float*)d_out, G);
}